// Round 1
// baseline (1470.670 us; speedup 1.0000x reference)
//
#include <hip/hip_runtime.h>

#define B_SZ   16384
#define T_STEPS 3
#define D_IN   2752
#define H_SZ   256
#define O_SZ   100
#define LDA    (T_STEPS * D_IN)   // 8256, row stride of dvs per batch row

// ---------------------------------------------------------------------------
// GEMM1: Hout[(t*B + b), n] = dot(dvs[b, t, :], W1[n, :]) + b1[n]
// 128x128 block tile, BK=32, 256 threads, 8x8 microtile, fp32 VALU.
// ---------------------------------------------------------------------------
#define BM 128
#define BN 128
#define BK 32

__global__ __launch_bounds__(256) void gemm1_kernel(
    const float* __restrict__ dvs, const float* __restrict__ W1,
    const float* __restrict__ b1, float* __restrict__ Hout) {
  __shared__ float At[BK][BM + 4];   // +4 pad: keeps 16B alignment, breaks worst conflicts
  __shared__ float Bt[BK][BN + 4];

  const int r0   = blockIdx.x * BM;        // global output row (t*B + b)
  const int t    = r0 >> 14;               // / 16384 (BM divides B, blocks never straddle t)
  const int brow = r0 & (B_SZ - 1);
  const float* Abase = dvs + (size_t)brow * LDA + (size_t)t * D_IN;
  const int n0 = blockIdx.y * BN;
  const float* Bbase = W1 + (size_t)n0 * D_IN;

  const int tid = threadIdx.x;
  const int tm = (tid >> 4) << 3;   // 0..120
  const int tn = (tid & 15) << 3;   // 0..120

  float acc[8][8] = {};

  for (int k0 = 0; k0 < D_IN; k0 += BK) {   // 86 chunks (32*86 == 2752)
    // stage 128x32 A-tile and B-tile, transposed to [k][m] for vector inner reads
#pragma unroll
    for (int j = 0; j < 4; j++) {
      int idx = tid + j * 256;        // 0..1023
      int row = idx >> 3;             // 0..127
      int kq  = (idx & 7) << 2;       // 0,4,...,28
      float4 a4 = *(const float4*)(Abase + (size_t)row * LDA + k0 + kq);
      float4 b4 = *(const float4*)(Bbase + (size_t)row * D_IN + k0 + kq);
      At[kq + 0][row] = a4.x; At[kq + 1][row] = a4.y;
      At[kq + 2][row] = a4.z; At[kq + 3][row] = a4.w;
      Bt[kq + 0][row] = b4.x; Bt[kq + 1][row] = b4.y;
      Bt[kq + 2][row] = b4.z; Bt[kq + 3][row] = b4.w;
    }
    __syncthreads();

#pragma unroll 8
    for (int k = 0; k < BK; k++) {
      float4 a0  = *(const float4*)&At[k][tm];
      float4 a1  = *(const float4*)&At[k][tm + 4];
      float4 bb0 = *(const float4*)&Bt[k][tn];
      float4 bb1 = *(const float4*)&Bt[k][tn + 4];
      float av[8] = {a0.x, a0.y, a0.z, a0.w, a1.x, a1.y, a1.z, a1.w};
      float bv[8] = {bb0.x, bb0.y, bb0.z, bb0.w, bb1.x, bb1.y, bb1.z, bb1.w};
#pragma unroll
      for (int i = 0; i < 8; i++)
#pragma unroll
        for (int jj = 0; jj < 8; jj++)
          acc[i][jj] += av[i] * bv[jj];
    }
    __syncthreads();
  }

#pragma unroll
  for (int i = 0; i < 8; i++) {
    float* dst = Hout + (size_t)(r0 + tm + i) * H_SZ + n0 + tn;
#pragma unroll
    for (int jj = 0; jj < 8; jj++) dst[jj] = acc[i][jj] + b1[n0 + tn + jj];
  }
}

// ---------------------------------------------------------------------------
// Tiled transpose: out[c*rows + r] = in[r*cols + c]
// ---------------------------------------------------------------------------
__global__ void transpose_kernel(const float* __restrict__ in,
                                 float* __restrict__ out, int rows, int cols) {
  __shared__ float tile[32][33];
  int bc = blockIdx.x * 32, br = blockIdx.y * 32;
  int tx = threadIdx.x, ty = threadIdx.y;   // 32 x 8
  for (int j = 0; j < 32; j += 8) {
    int r = br + ty + j, c = bc + tx;
    if (r < rows && c < cols) tile[ty + j][tx] = in[(size_t)r * cols + c];
  }
  __syncthreads();
  for (int j = 0; j < 32; j += 8) {
    int c = bc + ty + j, r = br + tx;
    if (c < cols && r < rows) out[(size_t)c * rows + r] = tile[tx][ty + j];
  }
}

// ---------------------------------------------------------------------------
// Recurrent LIF chain: one block per batch row, 256 threads (= H neurons).
// v1/v2/v3 carried in registers across T=3. Layers 2/3 exploit spike sparsity
// via ballot-compacted active lists; W2T/W3T reads are coalesced.
// Deterministic accumulation order (ascending neuron index).
// ---------------------------------------------------------------------------
__global__ __launch_bounds__(256) void recurrent_kernel(
    const float* __restrict__ H, const float* __restrict__ W2T,
    const float* __restrict__ b2, const float* __restrict__ W3T,
    const float* __restrict__ b3, float* __restrict__ out) {
  const int b = blockIdx.x;
  const int tid = threadIdx.x;
  const int lane = tid & 63, wv = tid >> 6;

  __shared__ unsigned long long wmask[4];
  __shared__ int lst[256];

  float v1 = 0.f, v2 = 0.f, v3 = 0.f;
  const float bias2 = b2[tid];
  const float bias3 = (tid < O_SZ) ? b3[tid] : 0.f;
  float out_s3 = 0.f;

  for (int t = 0; t < T_STEPS; t++) {
    float h1 = H[((size_t)t * B_SZ + b) * H_SZ + tid];
    v1 = v1 + 0.5f * (h1 - v1);
    bool s1 = (v1 >= 1.0f);
    if (s1) v1 = 0.f;

    unsigned long long m = __ballot(s1);
    __syncthreads();                      // prev iteration's lst/wmask readers done
    if (lane == 0) wmask[wv] = m;
    __syncthreads();
    int base = 0;
#pragma unroll
    for (int w = 0; w < 4; w++)
      if (w < wv) base += __popcll(wmask[w]);
    int total1 = __popcll(wmask[0]) + __popcll(wmask[1]) +
                 __popcll(wmask[2]) + __popcll(wmask[3]);
    if (s1) lst[base + __popcll(m & ((1ull << lane) - 1ull))] = tid;
    __syncthreads();

    float h2 = bias2;
    for (int i = 0; i < total1; i++)
      h2 += W2T[(size_t)lst[i] * H_SZ + tid];
    v2 = v2 + 0.5f * (h2 - v2);
    bool s2 = (v2 >= 1.0f);
    if (s2) v2 = 0.f;

    m = __ballot(s2);
    __syncthreads();                      // h2-loop lst readers done
    if (lane == 0) wmask[wv] = m;
    __syncthreads();
    base = 0;
#pragma unroll
    for (int w = 0; w < 4; w++)
      if (w < wv) base += __popcll(wmask[w]);
    int total2 = __popcll(wmask[0]) + __popcll(wmask[1]) +
                 __popcll(wmask[2]) + __popcll(wmask[3]);
    if (s2) lst[base + __popcll(m & ((1ull << lane) - 1ull))] = tid;
    __syncthreads();

    if (tid < O_SZ) {
      float h3 = bias3;
      for (int i = 0; i < total2; i++)
        h3 += W3T[(size_t)lst[i] * O_SZ + tid];
      v3 = v3 + 0.5f * (h3 - v3);
      bool s3 = (v3 >= 1.0f);
      if (s3) v3 = 0.f;
      out_s3 = s3 ? 1.0f : 0.0f;
    }
  }
  if (tid < O_SZ) out[(size_t)b * O_SZ + tid] = out_s3;
}

// ---------------------------------------------------------------------------
extern "C" void kernel_launch(void* const* d_in, const int* in_sizes, int n_in,
                              void* d_out, int out_size, void* d_ws, size_t ws_size,
                              hipStream_t stream) {
  const float* dvs = (const float*)d_in[0];
  const float* W1  = (const float*)d_in[1];
  const float* b1  = (const float*)d_in[2];
  const float* W2  = (const float*)d_in[3];
  const float* b2  = (const float*)d_in[4];
  const float* W3  = (const float*)d_in[5];
  const float* b3  = (const float*)d_in[6];
  float* out = (float*)d_out;

  char* ws = (char*)d_ws;
  float* Hbuf = (float*)ws;                                   // 49152*256 f32 = 50.3 MB
  float* W2T  = (float*)(ws + (size_t)T_STEPS * B_SZ * H_SZ * 4);
  float* W3T  = W2T + H_SZ * H_SZ;                            // [256][100]

  dim3 tb(32, 8);
  hipLaunchKernelGGL(transpose_kernel, dim3(8, 8), tb, 0, stream, W2, W2T, H_SZ, H_SZ);
  hipLaunchKernelGGL(transpose_kernel, dim3(8, 4), tb, 0, stream, W3, W3T, O_SZ, H_SZ);
  hipLaunchKernelGGL(gemm1_kernel, dim3((T_STEPS * B_SZ) / BM, H_SZ / BN), dim3(256),
                     0, stream, dvs, W1, b1, Hbuf);
  hipLaunchKernelGGL(recurrent_kernel, dim3(B_SZ), dim3(256), 0, stream,
                     Hbuf, W2T, b2, W3T, b3, out);
}

// Round 2
// 949.162 us; speedup vs baseline: 1.5494x; 1.5494x over previous
//
#include <hip/hip_runtime.h>

#define B_SZ    16384
#define T_STEPS 3
#define D_IN    2752
#define H_SZ    256
#define O_SZ    100
#define LDA     (T_STEPS * D_IN)   // 8256 floats, dvs row stride per batch row

typedef short bf16x8 __attribute__((ext_vector_type(8)));   // 8 bf16 = 4 VGPRs
typedef float f32x4  __attribute__((ext_vector_type(4)));

__device__ __forceinline__ unsigned short f2bf(float x) {
  union { float f; unsigned int u; } v; v.f = x;
  unsigned int r = v.u + 0x7FFFu + ((v.u >> 16) & 1u);   // RNE
  return (unsigned short)(r >> 16);
}

// ---------------------------------------------------------------------------
// W1 fp32 -> bf16 (layout preserved: [256][2752], k contiguous)
// 704512 elems / 4 per thread / 256 threads = 688 blocks
// ---------------------------------------------------------------------------
__global__ void cvt_w1_kernel(const float* __restrict__ W1,
                              unsigned short* __restrict__ W1bf) {
  int i = (blockIdx.x * 256 + threadIdx.x) * 4;
  float4 v = *(const float4*)(W1 + i);
  unsigned short o[4] = {f2bf(v.x), f2bf(v.y), f2bf(v.z), f2bf(v.w)};
  *(uint2*)(W1bf + i) = *(uint2*)o;
}

// ---------------------------------------------------------------------------
// GEMM1 (bf16 MFMA): Hout[(t*B+b), n] = dot(dvs[b,t,:], W1[n,:]) + b1[n]
// BM=64, BN=256 (full N: A read exactly once), BK=32, 256 thr = 4 waves.
// Wave w owns n in [64w, 64w+64): 4x4 grid of 16x16x32 MFMAs.
// A is fp32 in HBM -> convert to bf16 during LDS staging.
// LDS rows padded to 40 ushorts (80 B = 20 banks -> <=2-way conflicts, free).
// ---------------------------------------------------------------------------
#define BM 64
#define BN 256
#define BK 32
#define LDK 40   // BK + 8 pad, in ushorts

__global__ __launch_bounds__(256) void gemm1_mfma_kernel(
    const float* __restrict__ dvs, const unsigned short* __restrict__ W1bf,
    const float* __restrict__ b1, float* __restrict__ Hout) {
  __shared__ unsigned short At[BM][LDK];   // 5120 B
  __shared__ unsigned short Bt[BN][LDK];   // 20480 B

  const int r0   = blockIdx.x * BM;        // output row (t*B+b); 256 blocks per t
  const int t    = r0 >> 14;
  const int brow = r0 & (B_SZ - 1);
  const float* Abase = dvs + (size_t)brow * LDA + t * D_IN;

  const int tid  = threadIdx.x;
  const int lane = tid & 63, wv = tid >> 6;
  const int wn0  = wv * 64;                // wave's n offset
  const int lrow = lane & 15;              // fragment row/col within 16
  const int kgrp = lane >> 4;              // 0..3 -> k-offset kgrp*8

  // staging map: A: thread -> (row = tid>>2, kq = (tid&3)*8), 8 floats
  const int s_row = tid >> 2;
  const int s_kq  = (tid & 3) << 3;
  const float* ap0 = Abase + (size_t)s_row * LDA + s_kq;
  const unsigned short* bp0 = W1bf + (size_t)tid * D_IN;   // B: thread = row n

  f32x4 acc[4][4] = {};

  for (int k0 = 0; k0 < D_IN; k0 += BK) {   // 86 iterations
    float4 a0 = *(const float4*)(ap0 + k0);
    float4 a1 = *(const float4*)(ap0 + k0 + 4);
    uint4 bv0 = *(const uint4*)(bp0 + k0);
    uint4 bv1 = *(const uint4*)(bp0 + k0 + 8);
    uint4 bv2 = *(const uint4*)(bp0 + k0 + 16);
    uint4 bv3 = *(const uint4*)(bp0 + k0 + 24);

    __syncthreads();   // previous iteration's fragment reads done

    unsigned short a8[8] = {f2bf(a0.x), f2bf(a0.y), f2bf(a0.z), f2bf(a0.w),
                            f2bf(a1.x), f2bf(a1.y), f2bf(a1.z), f2bf(a1.w)};
    *(uint4*)&At[s_row][s_kq] = *(uint4*)a8;
    *(uint4*)&Bt[tid][0]  = bv0;
    *(uint4*)&Bt[tid][8]  = bv1;
    *(uint4*)&Bt[tid][16] = bv2;
    *(uint4*)&Bt[tid][24] = bv3;

    __syncthreads();

    bf16x8 af[4], bfr[4];
#pragma unroll
    for (int m = 0; m < 4; m++)
      af[m] = *(const bf16x8*)&At[m * 16 + lrow][kgrp * 8];
#pragma unroll
    for (int n = 0; n < 4; n++)
      bfr[n] = *(const bf16x8*)&Bt[wn0 + n * 16 + lrow][kgrp * 8];
#pragma unroll
    for (int m = 0; m < 4; m++)
#pragma unroll
      for (int n = 0; n < 4; n++)
        acc[m][n] = __builtin_amdgcn_mfma_f32_16x16x32_bf16(
            af[m], bfr[n], acc[m][n], 0, 0, 0);
  }

  // epilogue: C layout col = lane&15, row = (lane>>4)*4 + reg
#pragma unroll
  for (int m = 0; m < 4; m++) {
    int gm = r0 + m * 16 + kgrp * 4;
#pragma unroll
    for (int n = 0; n < 4; n++) {
      int gn = wn0 + n * 16 + lrow;
      float bias = b1[gn];
#pragma unroll
      for (int r = 0; r < 4; r++)
        Hout[(size_t)(gm + r) * H_SZ + gn] = acc[m][n][r] + bias;
    }
  }
}

// ---------------------------------------------------------------------------
// Tiled transpose: out[c*rows + r] = in[r*cols + c]
// ---------------------------------------------------------------------------
__global__ void transpose_kernel(const float* __restrict__ in,
                                 float* __restrict__ out, int rows, int cols) {
  __shared__ float tile[32][33];
  int bc = blockIdx.x * 32, br = blockIdx.y * 32;
  int tx = threadIdx.x, ty = threadIdx.y;   // 32 x 8
  for (int j = 0; j < 32; j += 8) {
    int r = br + ty + j, c = bc + tx;
    if (r < rows && c < cols) tile[ty + j][tx] = in[(size_t)r * cols + c];
  }
  __syncthreads();
  for (int j = 0; j < 32; j += 8) {
    int c = bc + ty + j, r = br + tx;
    if (c < cols && r < rows) out[(size_t)c * rows + r] = tile[tx][ty + j];
  }
}

// ---------------------------------------------------------------------------
// Recurrent LIF chain v2: one WAVE per 8 batch rows. No LDS, no barriers.
// Spike sets kept as 4x u64 ballot masks (wave-uniform); layer-2 gather does
// 4 independent coalesced 256B row loads per spiking neuron (L2-resident).
// Layer-3 gather almost never executes (v2 std ~0.2 << 1.0 threshold).
// ---------------------------------------------------------------------------
__global__ __launch_bounds__(256) void recurrent2_kernel(
    const float* __restrict__ H, const float* __restrict__ W2T,
    const float* __restrict__ b2, const float* __restrict__ W3T,
    const float* __restrict__ b3, float* __restrict__ out) {
  const int tid = threadIdx.x, lane = tid & 63, wv = tid >> 6;
  const int b0 = blockIdx.x * 32 + wv * 8;

  float b2v[4];
#pragma unroll
  for (int q = 0; q < 4; q++) b2v[q] = b2[lane + 64 * q];
  const float b3a = b3[lane];
  const float b3b = (lane < O_SZ - 64) ? b3[64 + lane] : 0.f;

  for (int bi = 0; bi < 8; bi++) {
    const int b = b0 + bi;
    float v1[4] = {0.f, 0.f, 0.f, 0.f};
    float v2[4] = {0.f, 0.f, 0.f, 0.f};
    float v3a = 0.f, v3b = 0.f, s3a = 0.f, s3b = 0.f;

    for (int t = 0; t < T_STEPS; t++) {
      const float* hp = H + ((size_t)t * B_SZ + b) * H_SZ;
      unsigned long long m1[4];
      float h2[4] = {b2v[0], b2v[1], b2v[2], b2v[3]};
#pragma unroll
      for (int q = 0; q < 4; q++) {
        float h1 = hp[lane + 64 * q];
        v1[q] = 0.5f * (v1[q] + h1);
        bool s = (v1[q] >= 1.0f);
        m1[q] = __ballot(s);
        if (s) v1[q] = 0.f;
      }
#pragma unroll
      for (int q = 0; q < 4; q++) {
        unsigned long long m = m1[q];
        while (m) {
          int n = 64 * q + __builtin_ctzll(m);
          m &= m - 1;
          const float* wp = W2T + (size_t)n * H_SZ + lane;
          h2[0] += wp[0]; h2[1] += wp[64]; h2[2] += wp[128]; h2[3] += wp[192];
        }
      }
      unsigned long long m2[4];
#pragma unroll
      for (int q = 0; q < 4; q++) {
        v2[q] = 0.5f * (v2[q] + h2[q]);
        bool s = (v2[q] >= 1.0f);
        m2[q] = __ballot(s);
        if (s) v2[q] = 0.f;
      }
      float h3a = b3a, h3b = b3b;
#pragma unroll
      for (int q = 0; q < 4; q++) {
        unsigned long long m = m2[q];
        while (m) {
          int j = 64 * q + __builtin_ctzll(m);
          m &= m - 1;
          h3a += W3T[(size_t)j * O_SZ + lane];
          if (lane < O_SZ - 64) h3b += W3T[(size_t)j * O_SZ + 64 + lane];
        }
      }
      v3a = 0.5f * (v3a + h3a);
      v3b = 0.5f * (v3b + h3b);
      bool sa = (v3a >= 1.0f), sb = (v3b >= 1.0f);
      if (sa) v3a = 0.f;
      if (sb) v3b = 0.f;
      if (t == T_STEPS - 1) { s3a = sa ? 1.f : 0.f; s3b = sb ? 1.f : 0.f; }
    }
    out[(size_t)b * O_SZ + lane] = s3a;
    if (lane < O_SZ - 64) out[(size_t)b * O_SZ + 64 + lane] = s3b;
  }
}

// ---------------------------------------------------------------------------
extern "C" void kernel_launch(void* const* d_in, const int* in_sizes, int n_in,
                              void* d_out, int out_size, void* d_ws, size_t ws_size,
                              hipStream_t stream) {
  const float* dvs = (const float*)d_in[0];
  const float* W1  = (const float*)d_in[1];
  const float* b1  = (const float*)d_in[2];
  const float* W2  = (const float*)d_in[3];
  const float* b2  = (const float*)d_in[4];
  const float* W3  = (const float*)d_in[5];
  const float* b3  = (const float*)d_in[6];
  float* out = (float*)d_out;

  char* ws = (char*)d_ws;
  float* Hbuf = (float*)ws;                                  // 50,331,648 B
  float* W2T  = (float*)(ws + (size_t)T_STEPS * B_SZ * H_SZ * 4);
  float* W3T  = W2T + H_SZ * H_SZ;                           // [j][o], 256x100
  unsigned short* W1bf = (unsigned short*)(W3T + H_SZ * O_SZ);

  dim3 tb(32, 8);
  hipLaunchKernelGGL(cvt_w1_kernel, dim3((H_SZ * D_IN) / 1024), dim3(256),
                     0, stream, W1, W1bf);
  hipLaunchKernelGGL(transpose_kernel, dim3(8, 8), tb, 0, stream, W2, W2T, H_SZ, H_SZ);
  hipLaunchKernelGGL(transpose_kernel, dim3(8, 4), tb, 0, stream, W3, W3T, O_SZ, H_SZ);
  hipLaunchKernelGGL(gemm1_mfma_kernel, dim3((T_STEPS * B_SZ) / BM), dim3(256),
                     0, stream, dvs, W1bf, b1, Hbuf);
  hipLaunchKernelGGL(recurrent2_kernel, dim3(B_SZ / 32), dim3(256), 0, stream,
                     Hbuf, W2T, b2, W3T, b3, out);
}